// Round 13
// baseline (144.287 us; speedup 1.0000x reference)
//
#include <hip/hip_runtime.h>
#include <math.h>

// Problem constants
#define NB    32
#define NHEAD 16
#define HW    1024

typedef float f32x4  __attribute__((ext_vector_type(4)));
typedef short bf16x2 __attribute__((ext_vector_type(2)));
typedef short bf16x4 __attribute__((ext_vector_type(4)));
typedef short bf16x8 __attribute__((ext_vector_type(8)));

__device__ __forceinline__ short f2bf(float f) {   // fp32 -> bf16 RNE
    union { float f; unsigned u; } c; c.f = f;
    unsigned r = c.u + 0x7FFFu + ((c.u >> 16) & 1u);
    return (short)(r >> 16);
}
#define SWZ(row) ((((row) >> 1) & 7) << 4)   // legacy (queryqk)
#define SWX(x)   ((((x) >> 2) & 7) << 4)     // fx image key
#define SWI(i)   ((((i) & 7)) << 4)          // fi image key
#define SWL(l)   ((((l) & 7)) << 4)          // fcn/wv key
#define MFMA16(a, b, c) __builtin_amdgcn_mfma_f32_16x16x32_bf16(a, b, c, 0, 0, 0)

__device__ __forceinline__ bf16x8 lds_ld8(const short* base, int off) {
    return *(const bf16x8*)((const char*)base + off);
}
__device__ __forceinline__ void lds_st4(short* base, int off, bf16x4 v) {
    *(bf16x4*)((char*)base + off) = v;
}

// ---------------------------------------------------------------------------
// Kernel 0: prep — bf16 casts / transposes / bias fold. (unchanged, passes)
// ---------------------------------------------------------------------------
__global__ __launch_bounds__(256) void prep_kernel(
        const float* __restrict__ Wq, const float* __restrict__ token,
        const float* __restrict__ Wk, const float* __restrict__ bq,
        short* __restrict__ Wq_bf, short* __restrict__ tok_t,
        short* __restrict__ Wk_t, float* __restrict__ qkb) {
    __shared__ float red[256];
    const int b = blockIdx.x, t = threadIdx.x;
    if (b < 1024) {
        const size_t idx = (size_t)b * 1024 + t * 4;
        const f32x4 v = *(const f32x4*)(Wq + idx);
        bf16x4 o; o[0]=f2bf(v[0]); o[1]=f2bf(v[1]); o[2]=f2bf(v[2]); o[3]=f2bf(v[3]);
        *(bf16x4*)(Wq_bf + idx) = o;
    } else if (b < 1056) {
        const int n = b - 1024;
        const int c0 = t * 4;
        float arr[4][16];
#pragma unroll
        for (int ci = 0; ci < 4; ++ci)
#pragma unroll
            for (int lq = 0; lq < 4; ++lq) {
                const f32x4 v = *(const f32x4*)(token + (size_t)n*16384 + (size_t)(c0+ci)*16 + lq*4);
#pragma unroll
                for (int e = 0; e < 4; ++e) arr[ci][lq*4+e] = v[e];
            }
#pragma unroll
        for (int l = 0; l < 16; ++l) {
            bf16x4 o; o[0]=f2bf(arr[0][l]); o[1]=f2bf(arr[1][l]); o[2]=f2bf(arr[2][l]); o[3]=f2bf(arr[3][l]);
            *(bf16x4*)(tok_t + (size_t)n*16384 + (size_t)l*1024 + c0) = o;
        }
    } else {
        const int h = b - 1056;
        const int i = t & 63, dq = t >> 6;
        float qs = 0.f; short wt[16];
#pragma unroll
        for (int k = 0; k < 16; ++k) {
            const int d = dq*16 + k;
            const float wv = Wk[(size_t)h*4096 + d*64 + i];
            qs += wv * bq[h*64 + d];
            wt[k] = f2bf(wv);
        }
#pragma unroll
        for (int kq = 0; kq < 4; ++kq) {
            bf16x4 o; o[0]=wt[kq*4]; o[1]=wt[kq*4+1]; o[2]=wt[kq*4+2]; o[3]=wt[kq*4+3];
            *(bf16x4*)(Wk_t + (size_t)h*4096 + i*64 + dq*16 + kq*4) = o;
        }
        red[t] = qs;
        __syncthreads();
        if (t < 64)
            qkb[h*64 + t] = (red[t] + red[t+64] + red[t+128] + red[t+192]) * 0.125f;
    }
}

// ---------------------------------------------------------------------------
// Kernel 1: fused query + qk (all-MFMA). (unchanged, passes)
// ---------------------------------------------------------------------------
__global__ __launch_bounds__(256) void queryqk_kernel(
        const short* __restrict__ Wq_bf, const short* __restrict__ tok_t,
        const short* __restrict__ Wk_t, const float* __restrict__ qkb,
        short* __restrict__ qk_bf) {
    __shared__ short q_ld[16 * 64];
    const int t = threadIdx.x, w = t >> 6, L = t & 63;
    const int lr = L & 15, hg = L >> 4;
    const int nh = blockIdx.x, n = nh >> 4, h = nh & 15;

    f32x4 acc = {0.f, 0.f, 0.f, 0.f};
    const short* aA = Wq_bf + (size_t)(h*64 + w*16 + lr) * 1024 + hg*8;
    const short* aB = tok_t + (size_t)n*16384 + (size_t)lr*1024 + hg*8;
#pragma unroll 4
    for (int ks = 0; ks < 32; ++ks) {
        const bf16x8 a = *(const bf16x8*)(aA + ks*32);
        const bf16x8 bb = *(const bf16x8*)(aB + ks*32);
        acc = MFMA16(a, bb, acc);
    }
    {
        bf16x4 qv; qv[0]=f2bf(acc[0]); qv[1]=f2bf(acc[1]); qv[2]=f2bf(acc[2]); qv[3]=f2bf(acc[3]);
        lds_st4(q_ld, (lr*128 + w*32 + hg*8) ^ SWZ(lr), qv);
    }
    __syncthreads();
    f32x4 a2 = {0.f, 0.f, 0.f, 0.f};
#pragma unroll
    for (int ks = 0; ks < 2; ++ks) {
        const bf16x8 a = *(const bf16x8*)(Wk_t + (size_t)h*4096 + (w*16 + lr)*64 + ks*32 + hg*8);
        const bf16x8 bb = lds_ld8(q_ld, (lr*128 + ks*64 + hg*16) ^ SWZ(lr));
        a2 = MFMA16(a, bb, a2);
    }
    const int i0 = w*16 + hg*4;
    bf16x4 qk4;
#pragma unroll
    for (int r = 0; r < 4; ++r)
        qk4[r] = f2bf(a2[r] * 0.125f + qkb[h*64 + i0 + r]);
    *(bf16x4*)(qk_bf + (size_t)nh*1024 + lr*64 + i0) = qk4;
}

// ---------------------------------------------------------------------------
// Kernel 2: PRODUCER/CONSUMER wave-specialized attention. One 1024-thread
// block per (n,h): waves 0-7 = producers (pure memory: feat load -> out0
// store -> double-buffered LDS images, prefetching next chunk before the
// barrier), waves 8-15 = consumers (pure compute: R12's verified logits/
// softmax/fc). One barrier per phase. The memory pipe stays fed during the
// whole consumer phase — kills the burst-drain that capped R7-R12 at
// ~2.5 TB/s. LDS 141 KB -> 1 block/CU (irrelevant now: overlap is intra-block).
// Consumer math identical to R12 (passed, absmax 4.9e-4).
// ---------------------------------------------------------------------------
__global__ __launch_bounds__(1024, 4) void attn_kernel(
        const float* __restrict__ feat, const short* __restrict__ qk_bf,
        const float* __restrict__ Wv, const float* __restrict__ bv,
        float* __restrict__ out0, float* __restrict__ out1) {
    __shared__ __align__(16) short fx[2][256 * 64];   // 2x32 KB [x][i] ^SWX; fx[0] reused: f32 dump
    __shared__ __align__(16) short fi[2][64 * 256];   // 2x32 KB [i][x] ^SWI; fi[0] reused: wv [d][i]
    __shared__ __align__(16) short p_scr[8 * 640];    // 10 KB per-consumer-wave P
    __shared__ __align__(16) short fcn[16 * 64];      // 2 KB
    __shared__ float red_m[128], red_z[128];          // 1 KB

    const int t = threadIdx.x;
    const bool prod = (t < 512);
    const int tc = t & 511;
    const int wc = tc >> 6, Lc = tc & 63;
    const int lr = Lc & 15, hg = Lc >> 4;
    const int nh = blockIdx.x, n = nh >> 4, h = nh & 15;
    const size_t fbase = (size_t)n*1048576 + (size_t)h*65536;

    // producer staging geometry (R12 mapping)
    const int sx = (tc & 63) * 4;
    const int si = (tc >> 6) * 8;

    bf16x8 qkA0, qkA1;
    if (!prod) {
        qkA0 = *(const bf16x8*)(qk_bf + (size_t)nh*1024 + lr*64 + hg*8);
        qkA1 = *(const bf16x8*)(qk_bf + (size_t)nh*1024 + lr*64 + 32 + hg*8);
    }

    f32x4 v[8];          // producer in-flight chunk (32 VGPR, producer threads only)
    f32x4 acc_fc[4];
#pragma unroll
    for (int ct = 0; ct < 4; ++ct) acc_fc[ct] = (f32x4){0.f,0.f,0.f,0.f};
    float mrun[4] = {-INFINITY,-INFINITY,-INFINITY,-INFINITY};
    float Zrun[4] = {0.f,0.f,0.f,0.f};
    short* p_w = p_scr + wc * 640;

    auto LOAD = [&](int cc) {
#pragma unroll
        for (int k = 0; k < 8; ++k)
            v[k] = *(const f32x4*)(feat + fbase + (size_t)(si+k)*1024 + cc*256 + sx);
    };
    auto PUBLISH = [&](int cc, int b) {   // v -> out0 + both LDS images
        bf16x4 vb[8];
#pragma unroll
        for (int k = 0; k < 8; ++k) {
            vb[k][0]=f2bf(v[k][0]); vb[k][1]=f2bf(v[k][1]);
            vb[k][2]=f2bf(v[k][2]); vb[k][3]=f2bf(v[k][3]);
        }
#pragma unroll
        for (int k = 0; k < 8; ++k) {
            const size_t g = fbase + (size_t)(si+k)*1024 + cc*256 + sx;
            *(f32x4*)(out0 + g) = v[k];
            lds_st4(fi[b], ((si+k)*512 + sx*2) ^ SWI(si+k), vb[k]);
        }
#pragma unroll
        for (int j = 0; j < 4; ++j) {
            const int x = sx + j;
#pragma unroll
            for (int kp = 0; kp < 4; ++kp) {
                const int i2 = si + 2*kp;
                bf16x2 pr; pr[0] = vb[2*kp][j]; pr[1] = vb[2*kp+1][j];
                *(bf16x2*)((char*)fx[b] + ((x*128 + i2*2) ^ SWX(x))) = pr;
            }
        }
    };
    auto CONSUME = [&](int b) {           // R12's logits + online softmax + fc
        f32x4 ST0 = {0.f,0.f,0.f,0.f}, ST1 = {0.f,0.f,0.f,0.f};
        const int xb0 = wc*32 + lr, xb1 = wc*32 + 16 + lr;
        ST0 = MFMA16(qkA0, lds_ld8(fx[b], (xb0*128 + hg*16)      ^ SWX(xb0)), ST0);
        ST0 = MFMA16(qkA1, lds_ld8(fx[b], (xb0*128 + 64 + hg*16) ^ SWX(xb0)), ST0);
        ST1 = MFMA16(qkA0, lds_ld8(fx[b], (xb1*128 + hg*16)      ^ SWX(xb1)), ST1);
        ST1 = MFMA16(qkA1, lds_ld8(fx[b], (xb1*128 + 64 + hg*16) ^ SWX(xb1)), ST1);
#pragma unroll
        for (int r = 0; r < 4; ++r) {
            float cm = fmaxf(ST0[r], ST1[r]);
#pragma unroll
            for (int msk = 8; msk >= 1; msk >>= 1)
                cm = fmaxf(cm, __shfl_xor(cm, msk));
            const float mnew = fmaxf(mrun[r], cm);
            const float rs = __expf(mrun[r] - mnew);
            const float p0 = __expf(ST0[r] - mnew);
            const float p1 = __expf(ST1[r] - mnew);
            const int row = (hg*4 + r) * 80;
            *(short*)((char*)p_w + row + lr*2)      = f2bf(p0);
            *(short*)((char*)p_w + row + 32 + lr*2) = f2bf(p1);
            float zc = p0 + p1;
#pragma unroll
            for (int msk = 8; msk >= 1; msk >>= 1)
                zc += __shfl_xor(zc, msk);
            Zrun[r] = Zrun[r] * rs + zc;
            mrun[r] = mnew;
#pragma unroll
            for (int ct = 0; ct < 4; ++ct) acc_fc[ct][r] *= rs;
        }
        const bf16x8 pA = lds_ld8(p_w, lr*80 + hg*16);
#pragma unroll
        for (int ct = 0; ct < 4; ++ct) {
            const int i = ct*16 + lr;
            const bf16x8 fB = lds_ld8(fi[b], (i*512 + wc*64 + hg*16) ^ SWI(i));
            acc_fc[ct] = MFMA16(pA, fB, acc_fc[ct]);
        }
    };

    // prologue: chunk 0 published, chunk 1 in flight
    if (prod) { LOAD(0); PUBLISH(0, 0); LOAD(1); }
    __syncthreads();

#pragma unroll 1   // keep per-phase live range small (R12 lesson)
    for (int c = 0; c < 4; ++c) {
        if (prod) {
            if (c < 3) PUBLISH(c+1, (c+1)&1);   // v holds chunk c+1
            if (c < 2) LOAD(c+2);               // prefetch: in flight across barrier
            if (c == 3) {                        // stage Wv into fi[0] (dead since phase 2)
                const int d = tc >> 3, i0 = (tc & 7) * 8;
                const f32x4 a = *(const f32x4*)(Wv + (size_t)h*4096 + d*64 + i0);
                const f32x4 b = *(const f32x4*)(Wv + (size_t)h*4096 + d*64 + i0 + 4);
                bf16x8 wb;
                wb[0]=f2bf(a[0]); wb[1]=f2bf(a[1]); wb[2]=f2bf(a[2]); wb[3]=f2bf(a[3]);
                wb[4]=f2bf(b[0]); wb[5]=f2bf(b[1]); wb[6]=f2bf(b[2]); wb[7]=f2bf(b[3]);
                *(bf16x8*)((char*)fi[0] + ((d*128 + i0*2) ^ SWL(d))) = wb;
            }
        } else {
            CONSUME(c & 1);
        }
        __syncthreads();
    }

    // ---- cross-wave merge (consumers only hold state) ----
    if (!prod && lr == 0) {
#pragma unroll
        for (int r = 0; r < 4; ++r) {
            red_m[wc*16 + hg*4 + r] = mrun[r];
            red_z[wc*16 + hg*4 + r] = Zrun[r];
        }
    }
    __syncthreads();
    if (!prod) {   // rescale own partials by exp(m_w - m_g), dump to fx[0] (dead)
        float sc[4];
#pragma unroll
        for (int r = 0; r < 4; ++r) {
            const int l = hg*4 + r;
            float m = red_m[l];
#pragma unroll
            for (int wp = 1; wp < 8; ++wp) m = fmaxf(m, red_m[wp*16 + l]);
            sc[r] = __expf(mrun[r] - m);
        }
#pragma unroll
        for (int ct = 0; ct < 4; ++ct) {
#pragma unroll
            for (int r = 0; r < 4; ++r) acc_fc[ct][r] *= sc[r];
            *(f32x4*)((char*)fx[0] + (wc*4 + ct)*1024 + Lc*16) = acc_fc[ct];
        }
    }
    __syncthreads();
    if (!prod && wc < 4) {   // reduce i-tile wc over 8 wave-partials -> fcn
        f32x4 s = (f32x4){0.f,0.f,0.f,0.f};
#pragma unroll
        for (int wp = 0; wp < 8; ++wp)
            s += *(const f32x4*)((const char*)fx[0] + (wp*4 + wc)*1024 + Lc*16);
#pragma unroll
        for (int r = 0; r < 4; ++r) {
            const int l = hg*4 + r;
            float m = red_m[l];
#pragma unroll
            for (int wp = 1; wp < 8; ++wp) m = fmaxf(m, red_m[wp*16 + l]);
            float Z = 0.f;
#pragma unroll
            for (int wp = 0; wp < 8; ++wp)
                Z += __expf(red_m[wp*16 + l] - m) * red_z[wp*16 + l];
            *(short*)((char*)fcn + ((l*128 + (wc*16 + lr)*2) ^ SWL(l))) = f2bf(s[r] / Z);
        }
    }
    __syncthreads();
    if (!prod && wc < 4) {   // tok[d][l] = Wv @ fcn + bv; wave wc owns d-tile wc
        f32x4 acc = (f32x4){0.f,0.f,0.f,0.f};
        const int dm = wc*16 + lr;
#pragma unroll
        for (int ks = 0; ks < 2; ++ks) {
            const bf16x8 a = lds_ld8(fi[0], (dm*128 + ks*64 + hg*16) ^ SWL(dm));
            const bf16x8 b = lds_ld8(fcn,   (lr*128 + ks*64 + hg*16) ^ SWL(lr));
            acc = MFMA16(a, b, acc);
        }
#pragma unroll
        for (int r = 0; r < 4; ++r) {
            const int d = wc*16 + hg*4 + r;
            out1[((size_t)n*1024 + h*64 + d)*16 + lr] = acc[r] + bv[h*64 + d];
        }
    }
}

// ---------------------------------------------------------------------------
extern "C" void kernel_launch(void* const* d_in, const int* in_sizes, int n_in,
                              void* d_out, int out_size, void* d_ws, size_t ws_size,
                              hipStream_t stream) {
    const float* feature = (const float*)d_in[0];
    const float* token   = (const float*)d_in[1];
    const float* Wq      = (const float*)d_in[2];
    const float* bq      = (const float*)d_in[3];
    const float* Wk      = (const float*)d_in[4];
    // d_in[5] = bk: provably unused (constant along softmax axis)
    const float* Wv      = (const float*)d_in[6];
    const float* bv      = (const float*)d_in[7];

    float* out0 = (float*)d_out;                      // feature passthrough
    float* out1 = out0 + (size_t)NB * 1024 * HW;      // tok [n][c][l]

    short* Wq_bf = (short*)d_ws;                               // 2 MB
    short* tok_t = Wq_bf + (size_t)1024 * 1024;                // 1 MB
    short* Wk_t  = tok_t + (size_t)NB * 16 * 1024;             // 128 KB
    short* qk_bf = Wk_t + (size_t)NHEAD * 64 * 64;             // 1 MB
    float* qkb   = (float*)(qk_bf + (size_t)NB * NHEAD * 1024);// 4 KB

    prep_kernel   <<<dim3(1072), 256, 0, stream>>>(Wq, token, Wk, bq, Wq_bf, tok_t, Wk_t, qkb);
    queryqk_kernel<<<dim3(NB * NHEAD), 256, 0, stream>>>(Wq_bf, tok_t, Wk_t, qkb, qk_bf);
    attn_kernel   <<<dim3(NB * NHEAD), 1024, 0, stream>>>(feature, qk_bf, Wv, bv, out0, out1);
}